// Round 4
// baseline (356.032 us; speedup 1.0000x reference)
//
#include <hip/hip_runtime.h>

// CTC greedy decode: B=1024, T=512, C=128, blank=C-1.
// One block per batch row, 512 threads (8 waves), ~4.6 KB LDS.
//
// Stage 1 (argmax per timestep): 4-lane teams, each lane owns 32 classes as
//   interleaved 16-B chunks (class idx = 16j + 4h + k), so each load
//   instruction covers 16 rows x contiguous 64 B. Depth-2 ping-pong register
//   buffers (A/B) keep 8-16 KB per wave in flight with partial vmcnt waits:
//   consume buf -> reissue its 8 loads for it+2 -> then reduce/store.
//   In-lane argmax = two independent 16-elem chains (ILP), strict > on
//   ascending indices = first occurrence. Cross-lane: u64 key
//   (value_bits<<32 | 127-idx), 2-step __shfl_xor (masks 1,2 -> DPP
//   quad_perm, no LDS) -- bit-exact (max value, min index) since inputs are
//   non-negative fp32.
//
// Stage 2 (collapse repeats + drop blanks): block prefix scan over valid
//   flags, scatter table[best] into LDS char row, coalesced int32 store.
//   (Validated absmax 0 in rounds 1-3; unchanged.)

constexpr int T_DIM = 512;
constexpr int C_DIM = 128;
constexpr int BLANK = C_DIM - 1;
constexpr int BLOCK = 512;
constexpr int TS_PER_ITER = BLOCK / 4;       // 128 timesteps per block-iteration
constexpr int N_ITER = T_DIM / TS_PER_ITER;  // 4

__device__ __forceinline__ void load8(float4 (&buf)[8], const float* p) {
    #pragma unroll
    for (int j = 0; j < 8; ++j) buf[j] = *(const float4*)(p + j * 16);
}

// In-lane argmax over this lane's 32 classes; idx = 16j + 4h + k.
__device__ __forceinline__ void lane_argmax(const float4 (&buf)[8], int h,
                                            float& bv, int& bi) {
    float bvA = -1.0f; int biA = 0;
    #pragma unroll
    for (int j = 0; j < 4; ++j) {
        const int i0 = 16 * j + 4 * h;
        if (buf[j].x > bvA) { bvA = buf[j].x; biA = i0;     }
        if (buf[j].y > bvA) { bvA = buf[j].y; biA = i0 + 1; }
        if (buf[j].z > bvA) { bvA = buf[j].z; biA = i0 + 2; }
        if (buf[j].w > bvA) { bvA = buf[j].w; biA = i0 + 3; }
    }
    float bvB = -1.0f; int biB = 64;
    #pragma unroll
    for (int j = 4; j < 8; ++j) {
        const int i0 = 16 * j + 4 * h;
        if (buf[j].x > bvB) { bvB = buf[j].x; biB = i0;     }
        if (buf[j].y > bvB) { bvB = buf[j].y; biB = i0 + 1; }
        if (buf[j].z > bvB) { bvB = buf[j].z; biB = i0 + 2; }
        if (buf[j].w > bvB) { bvB = buf[j].w; biB = i0 + 3; }
    }
    // All chain-B indices exceed chain-A indices: strict > keeps first occurrence.
    if (bvB > bvA) { bvA = bvB; biA = biB; }
    bv = bvA; bi = biA;
}

// Cross-lane (4-lane team) max with min-index tie-break; all lanes get result.
__device__ __forceinline__ int team_reduce(float bv, int bi) {
    unsigned long long key =
        ((unsigned long long)__float_as_uint(bv) << 32) | (unsigned)(127 - bi);
    #pragma unroll
    for (int m = 1; m <= 2; m <<= 1) {
        const unsigned long long ok = __shfl_xor(key, m);
        if (ok > key) key = ok;
    }
    return 127 - (int)(key & 127u);
}

__global__ __launch_bounds__(BLOCK, 4) void ctc_decode_kernel(
    const float* __restrict__ probs,
    const int* __restrict__ table,
    const int* __restrict__ defc_p,
    int* __restrict__ out)
{
    __shared__ int s_best[T_DIM];
    __shared__ int s_chars[T_DIM];
    __shared__ int s_table[C_DIM];
    __shared__ int s_wavesums[BLOCK / 64];

    const int b    = blockIdx.x;
    const int tid  = threadIdx.x;
    const int lane = tid & 63;
    const int wave = tid >> 6;

    if (tid < C_DIM) s_table[tid] = table[tid];
    const int defc = defc_p[0];

    const float* row = probs + (size_t)b * T_DIM * C_DIM;

    // ---- Stage 1: per-timestep argmax, depth-2 ping-pong from global ----
    const int g = lane >> 2;   // timestep slot within this wave's group of 16
    const int h = lane & 3;    // lane within the 4-lane team

    const int ts_local = wave * 16 + g;                 // timestep within iter
    const float* base  = row + (size_t)ts_local * C_DIM + h * 4;
    const size_t step  = (size_t)TS_PER_ITER * C_DIM;   // floats per iter

    float4 bufA[8], bufB[8];
    load8(bufA, base);                                  // it=0
    load8(bufB, base + step);                           // it=1

    float bv; int bi;

    // it = 0: consume A, refill A for it=2, then reduce/store.
    lane_argmax(bufA, h, bv, bi);
    load8(bufA, base + 2 * step);
    {
        const int idx = team_reduce(bv, bi);
        if (h == 0) s_best[0 * TS_PER_ITER + ts_local] = idx;
    }
    // it = 1: consume B, refill B for it=3.
    lane_argmax(bufB, h, bv, bi);
    load8(bufB, base + 3 * step);
    {
        const int idx = team_reduce(bv, bi);
        if (h == 0) s_best[1 * TS_PER_ITER + ts_local] = idx;
    }
    // it = 2
    lane_argmax(bufA, h, bv, bi);
    {
        const int idx = team_reduce(bv, bi);
        if (h == 0) s_best[2 * TS_PER_ITER + ts_local] = idx;
    }
    // it = 3
    lane_argmax(bufB, h, bv, bi);
    {
        const int idx = team_reduce(bv, bi);
        if (h == 0) s_best[3 * TS_PER_ITER + ts_local] = idx;
    }
    __syncthreads();

    // ---- Stage 2: valid mask + block inclusive scan ----
    const int best_t = s_best[tid];
    const int prev   = (tid > 0) ? s_best[tid - 1] : -1;
    const int valid  = (best_t != prev && best_t != BLANK) ? 1 : 0;

    int scan = valid;
    #pragma unroll
    for (int off = 1; off < 64; off <<= 1) {
        const int vv = __shfl_up(scan, off);
        if (lane >= off) scan += vv;
    }
    if (lane == 63) s_wavesums[wave] = scan;
    __syncthreads();
    if (tid == 0) {
        int acc = 0;
        #pragma unroll
        for (int w = 0; w < BLOCK / 64; ++w) {
            const int tmp = s_wavesums[w];
            s_wavesums[w] = acc;
            acc += tmp;
        }
    }
    __syncthreads();
    const int pos = scan + s_wavesums[wave] - 1;  // exclusive position among valid

    // ---- Scatter chars into LDS row, then coalesced store ----
    s_chars[tid] = defc;
    __syncthreads();
    if (valid) s_chars[pos] = s_table[best_t];
    __syncthreads();
    out[(size_t)b * T_DIM + tid] = s_chars[tid];
}

extern "C" void kernel_launch(void* const* d_in, const int* in_sizes, int n_in,
                              void* d_out, int out_size, void* d_ws, size_t ws_size,
                              hipStream_t stream) {
    const float* probs = (const float*)d_in[0];
    const int*   table = (const int*)d_in[1];
    const int*   defc  = (const int*)d_in[2];
    int*         out   = (int*)d_out;

    const int B = out_size / T_DIM;  // 1024
    ctc_decode_kernel<<<dim3(B), dim3(BLOCK), 0, stream>>>(probs, table, defc, out);
}